// Round 23
// baseline (142.091 us; speedup 1.0000x reference)
//
#include <hip/hip_runtime.h>
#include <math.h>

#define BTOT   32768
#define LAT    128
#define H      17
#define G4     68      // 4*H
#define TSTEPS 50
#define NPR    102     // projection rows: 68 (W_ih) + 17 (W_h0) + 17 (W_c0)
#define WPAD   40      // Wbuf row stride (k-quarter staging, R14-proven)
#define XPAD   132

#define NW     4              // waves per block (small blocks -> decorrelated)
#define RPB    12             // 3 rows per wave, 51/64 lanes active
#define TPB    256

typedef float float2v __attribute__((ext_vector_type(2)));

// x_tile stride 132: rows r,r+8 alias -> 2-bit XOR key (R13/R14-proven).
#define XSWZ(r, c4)   ((c4) ^ ((((r) >> 3) & 3) << 2))
// Wbuf stride 40: rows r,r+4 alias -> key on bits 2-3 (R14-proven).
#define WSWZ(row, c4) ((c4) ^ ((((row) >> 2) & 3) << 2))

// f32-only gates (R9: recurrence amplifies per-step error ~1e3x; f16 fails).
__device__ __forceinline__ float fsigmoid(float x) {
    float e = __expf(-x);
    return __builtin_amdgcn_rcpf(1.0f + e);
}
// tanh(x) = 1 - 2*rcp(exp(2x)+1); +inf -> 1, -inf -> -1, no divide.
__device__ __forceinline__ float ftanhf(float x) {
    float e = __expf(2.0f * x);
    float t = __builtin_amdgcn_rcpf(e + 1.0f);
    return fmaf(-2.0f, t, 1.0f);
}

// (256,4): unified reg cap 128. R20-proven structure: 16 waves/CU, 45% occ.
__global__ __launch_bounds__(TPB, 4)
void lstm_fused(const float* __restrict__ x,
                const float* __restrict__ W_h0, const float* __restrict__ b_h0,
                const float* __restrict__ W_c0, const float* __restrict__ b_c0,
                const float* __restrict__ W_ih, const float* __restrict__ W_hh,
                const float* __restrict__ b_ih, const float* __restrict__ b_hh,
                float* __restrict__ out)
{
    __shared__ __align__(16) float x_tile[RPB][XPAD];   //  6.3 KB
    __shared__ __align__(16) float Wbuf[NPR][WPAD];     // 16.3 KB (one k-quarter)
    __shared__ __align__(16) float Wl[G4 * H];          //  4.6 KB (W_hh f32)
    __shared__ __align__(16) float hbuf[NW][3][20];     //  1.0 KB
    // total 28.2 KB; occupancy reg-capped at 4 blocks/CU (R20: 45%).

    const int t    = threadIdx.x;
    const int w    = t >> 6;
    const int lane = t & 63;
    const bool active = lane < 3 * H;         // 51
    const int rl = active ? (lane / H) : 0;   // 0..2
    const int j  = active ? (lane % H) : 0;   // 0..16
    const int r0 = w * 3 + rl;                // block-local row 0..11
    const int grow0 = blockIdx.x * RPB;
    int grow = grow0 + r0;
    const bool valid = active && (grow < BTOT);
    if (grow >= BTOT) grow = BTOT - 1;

    // ---- stage x tile (rows clamped) + W_hh; all 256 threads ----
    for (int i = t; i < RPB * 32; i += TPB) {              // 384 float4
        int rr = i >> 5, c4 = (i & 31) * 4;
        int gr = grow0 + rr; if (gr >= BTOT) gr = BTOT - 1;
        *(float4*)&x_tile[rr][XSWZ(rr, c4)] = *(const float4*)(x + (size_t)gr * LAT + c4);
    }
    for (int i = t; i < G4 * H; i += TPB) Wl[i] = W_hh[i];

    // ---- phase 1: projections, four k-quarters of 32 (R14-proven layout) ----
    float acc[6] = {0.f, 0.f, 0.f, 0.f, 0.f, 0.f};         // i,f,g,o, h0, c0
    const int rows6[6] = { j, 17 + j, 34 + j, 51 + j, 68 + j, 85 + j };
    for (int qh = 0; qh < 4; ++qh) {
        __syncthreads();  // qh=0: x_tile/Wl ready; else WAR on Wbuf
        for (int i = t; i < NPR * 8; i += TPB) {           // 8 float4 per quarter-row
            int row = i >> 3, c4 = (i & 7) * 4;
            const float* src = (row < G4) ? (W_ih + row * LAT)
                             : (row < 85) ? (W_h0 + (row - G4) * LAT)
                                          : (W_c0 + (row - 85) * LAT);
            *(float4*)&Wbuf[row][WSWZ(row, c4)] = *(const float4*)(src + qh * 32 + c4);
        }
        __syncthreads();  // quarter ready
        for (int kb = 0; kb < 8; ++kb) {
            const int xc = qh * 32 + kb * 4;
            float4 xv = *(const float4*)&x_tile[r0][XSWZ(r0, xc)];
#pragma unroll
            for (int p = 0; p < 6; ++p) {
                const int row = rows6[p];
                float4 wv = *(const float4*)&Wbuf[row][WSWZ(row, kb * 4)];
                acc[p] = fmaf(xv.x, wv.x, acc[p]);
                acc[p] = fmaf(xv.y, wv.y, acc[p]);
                acc[p] = fmaf(xv.z, wv.z, acc[p]);
                acc[p] = fmaf(xv.w, wv.w, acc[p]);
            }
        }
    }

    const float xgi = acc[0] + b_ih[j]      + b_hh[j];
    const float xgf = acc[1] + b_ih[17 + j] + b_hh[17 + j];
    const float xgg = acc[2] + b_ih[34 + j] + b_hh[34 + j];
    const float xgo = acc[3] + b_ih[51 + j] + b_hh[51 + j];
    float h = acc[4] + b_h0[j];
    float c = acc[5] + b_c0[j];

    // ---- W_hh rows -> 32 packed f32 pairs + 4 scalars (k=16) ----
    float2v Wip[8], Wfp[8], Wgp[8], Wop[8];
#pragma unroll
    for (int p = 0; p < 8; ++p) {
        Wip[p] = float2v{ Wl[(0 * H + j) * H + 2 * p], Wl[(0 * H + j) * H + 2 * p + 1] };
        Wfp[p] = float2v{ Wl[(1 * H + j) * H + 2 * p], Wl[(1 * H + j) * H + 2 * p + 1] };
        Wgp[p] = float2v{ Wl[(2 * H + j) * H + 2 * p], Wl[(2 * H + j) * H + 2 * p + 1] };
        Wop[p] = float2v{ Wl[(3 * H + j) * H + 2 * p], Wl[(3 * H + j) * H + 2 * p + 1] };
        asm volatile("" : "+v"(Wip[p]), "+v"(Wfp[p]), "+v"(Wgp[p]), "+v"(Wop[p]));
    }
    float Wi16 = Wl[(0 * H + j) * H + 16];
    float Wf16 = Wl[(1 * H + j) * H + 16];
    float Wg16 = Wl[(2 * H + j) * H + 16];
    float Wo16 = Wl[(3 * H + j) * H + 16];

    // ---- phase 2: single-set recurrence, zero barriers; dot = ONE asm block ----
    // All 32 W-pairs are simultaneous "v" operands of one asm block: AGPR
    // banking would now cost 68 copies per block entry vs direct arch
    // residence (113 regs <= 128 cap) -> allocator should keep W in VGPRs.
    const float* hb = &hbuf[w][rl][0];
    float* orow = out + (size_t)grow * (TSTEPS * H) + j;

    for (int tt = 0; tt < TSTEPS; ++tt) {
        if (active) hbuf[w][rl][j] = h;
        // same-wave write->read on hbuf: compiler inserts lgkmcnt wait

        float4 f0 = *(const float4*)&hb[0];
        float4 f1 = *(const float4*)&hb[4];
        float4 f2 = *(const float4*)&hb[8];
        float4 f3 = *(const float4*)&hb[12];
        float  h16 = hb[16];
        float2v p0 = { f0.x, f0.y }, p1 = { f0.z, f0.w };
        float2v p2 = { f1.x, f1.y }, p3 = { f1.z, f1.w };
        float2v p4 = { f2.x, f2.y }, p5 = { f2.z, f2.w };
        float2v p6 = { f3.x, f3.y }, p7 = { f3.z, f3.w };

        float2v vi = { xgi, 0.0f }, vf = { xgf, 0.0f };
        float2v vg = { xgg, 0.0f }, vo = { xgo, 0.0f };
        asm volatile(
            "v_pk_fma_f32 %[ai], %[i0], %[p0], %[ai]\n\t"
            "v_pk_fma_f32 %[af], %[f0], %[p0], %[af]\n\t"
            "v_pk_fma_f32 %[ag], %[g0], %[p0], %[ag]\n\t"
            "v_pk_fma_f32 %[ao], %[o0], %[p0], %[ao]\n\t"
            "v_pk_fma_f32 %[ai], %[i1], %[p1], %[ai]\n\t"
            "v_pk_fma_f32 %[af], %[f1], %[p1], %[af]\n\t"
            "v_pk_fma_f32 %[ag], %[g1], %[p1], %[ag]\n\t"
            "v_pk_fma_f32 %[ao], %[o1], %[p1], %[ao]\n\t"
            "v_pk_fma_f32 %[ai], %[i2], %[p2], %[ai]\n\t"
            "v_pk_fma_f32 %[af], %[f2], %[p2], %[af]\n\t"
            "v_pk_fma_f32 %[ag], %[g2], %[p2], %[ag]\n\t"
            "v_pk_fma_f32 %[ao], %[o2], %[p2], %[ao]\n\t"
            "v_pk_fma_f32 %[ai], %[i3], %[p3], %[ai]\n\t"
            "v_pk_fma_f32 %[af], %[f3], %[p3], %[af]\n\t"
            "v_pk_fma_f32 %[ag], %[g3], %[p3], %[ag]\n\t"
            "v_pk_fma_f32 %[ao], %[o3], %[p3], %[ao]\n\t"
            "v_pk_fma_f32 %[ai], %[i4], %[p4], %[ai]\n\t"
            "v_pk_fma_f32 %[af], %[f4], %[p4], %[af]\n\t"
            "v_pk_fma_f32 %[ag], %[g4], %[p4], %[ag]\n\t"
            "v_pk_fma_f32 %[ao], %[o4], %[p4], %[ao]\n\t"
            "v_pk_fma_f32 %[ai], %[i5], %[p5], %[ai]\n\t"
            "v_pk_fma_f32 %[af], %[f5], %[p5], %[af]\n\t"
            "v_pk_fma_f32 %[ag], %[g5], %[p5], %[ag]\n\t"
            "v_pk_fma_f32 %[ao], %[o5], %[p5], %[ao]\n\t"
            "v_pk_fma_f32 %[ai], %[i6], %[p6], %[ai]\n\t"
            "v_pk_fma_f32 %[af], %[f6], %[p6], %[af]\n\t"
            "v_pk_fma_f32 %[ag], %[g6], %[p6], %[ag]\n\t"
            "v_pk_fma_f32 %[ao], %[o6], %[p6], %[ao]\n\t"
            "v_pk_fma_f32 %[ai], %[i7], %[p7], %[ai]\n\t"
            "v_pk_fma_f32 %[af], %[f7], %[p7], %[af]\n\t"
            "v_pk_fma_f32 %[ag], %[g7], %[p7], %[ag]\n\t"
            "v_pk_fma_f32 %[ao], %[o7], %[p7], %[ao]"
            : [ai]"+v"(vi), [af]"+v"(vf), [ag]"+v"(vg), [ao]"+v"(vo)
            : [i0]"v"(Wip[0]), [i1]"v"(Wip[1]), [i2]"v"(Wip[2]), [i3]"v"(Wip[3]),
              [i4]"v"(Wip[4]), [i5]"v"(Wip[5]), [i6]"v"(Wip[6]), [i7]"v"(Wip[7]),
              [f0]"v"(Wfp[0]), [f1]"v"(Wfp[1]), [f2]"v"(Wfp[2]), [f3]"v"(Wfp[3]),
              [f4]"v"(Wfp[4]), [f5]"v"(Wfp[5]), [f6]"v"(Wfp[6]), [f7]"v"(Wfp[7]),
              [g0]"v"(Wgp[0]), [g1]"v"(Wgp[1]), [g2]"v"(Wgp[2]), [g3]"v"(Wgp[3]),
              [g4]"v"(Wgp[4]), [g5]"v"(Wgp[5]), [g6]"v"(Wgp[6]), [g7]"v"(Wgp[7]),
              [o0]"v"(Wop[0]), [o1]"v"(Wop[1]), [o2]"v"(Wop[2]), [o3]"v"(Wop[3]),
              [o4]"v"(Wop[4]), [o5]"v"(Wop[5]), [o6]"v"(Wop[6]), [o7]"v"(Wop[7]),
              [p0]"v"(p0), [p1]"v"(p1), [p2]"v"(p2), [p3]"v"(p3),
              [p4]"v"(p4), [p5]"v"(p5), [p6]"v"(p6), [p7]"v"(p7));

        float ai = vi.x + vi.y; ai = fmaf(Wi16, h16, ai);
        float af = vf.x + vf.y; af = fmaf(Wf16, h16, af);
        float ag = vg.x + vg.y; ag = fmaf(Wg16, h16, ag);
        float ao = vo.x + vo.y; ao = fmaf(Wo16, h16, ao);

        const float ig = fsigmoid(ai), fg = fsigmoid(af);
        const float gv = ftanhf(ag),  og = fsigmoid(ao);
        c = fmaf(fg, c, ig * gv);
        h = og * ftanhf(c);

        if (valid) orow[tt * H] = h;
    }
}

extern "C" void kernel_launch(void* const* d_in, const int* in_sizes, int n_in,
                              void* d_out, int out_size, void* d_ws, size_t ws_size,
                              hipStream_t stream)
{
    const float* x    = (const float*)d_in[0];
    const float* W_h0 = (const float*)d_in[1];
    const float* b_h0 = (const float*)d_in[2];
    const float* W_c0 = (const float*)d_in[3];
    const float* b_c0 = (const float*)d_in[4];
    const float* W_ih = (const float*)d_in[5];
    const float* W_hh = (const float*)d_in[6];
    const float* b_ih = (const float*)d_in[7];
    const float* b_hh = (const float*)d_in[8];
    float* out = (float*)d_out;

    (void)d_ws; (void)ws_size;  // no workspace used

    const int nblk = (BTOT + RPB - 1) / RPB;   // 2731
    hipLaunchKernelGGL(lstm_fused, dim3(nblk), dim3(TPB), 0, stream,
                       x, W_h0, b_h0, W_c0, b_c0, W_ih, W_hh, b_ih, b_hh, out);
}